// Round 1
// baseline (6893.192 us; speedup 1.0000x reference)
//
#include <hip/hip_runtime.h>
#include <math.h>

#define DIM 512
#define NCLS 100
#define NS 2048
#define DD (DIM*DIM)
#define SHRINKV 1e-4f

typedef short bf16x8 __attribute__((ext_vector_type(8)));
typedef float f32x4 __attribute__((ext_vector_type(4)));

static __device__ __forceinline__ short f2bf(float f) {
  unsigned int u = __float_as_uint(f);
  u += 0x7FFFu + ((u >> 16) & 1u);   // round-to-nearest-even
  return (short)(u >> 16);
}

// aux[0] = sum(cK); aux[1+k] zeroed (prep atomically accumulates fro^2 there)
__global__ void aux_kernel(const float* __restrict__ cK, float* __restrict__ aux) {
  __shared__ float red[128];
  int t = threadIdx.x;
  float v = (t < NCLS) ? cK[t] : 0.f;
  if (t < NCLS) aux[1 + t] = 0.f;
  red[t] = v;
  __syncthreads();
  for (int o = 64; o > 0; o >>= 1) {
    if (t < o) red[t] += red[t + o];
    __syncthreads();
  }
  if (t == 0) aux[0] = red[0];
}

// Build M_k = (1-sh)*(0.5*(SigmaK_k+Sigma)) + sh*I ; accumulate ||RegSigma||_F^2
__global__ __launch_bounds__(256) void prep_kernel(const float* __restrict__ SigmaK,
                                                   const float* __restrict__ Sigma,
                                                   float* __restrict__ M,
                                                   float* __restrict__ aux) {
  int b = blockIdx.x;
  int k = b >> 2, chunk = b & 3;
  const float* Sk = SigmaK + (size_t)k * DD;
  float* Mk = M + (size_t)k * DD;
  int base0 = chunk << 16;
  float fro = 0.f;
  const float oms = 1.0f - SHRINKV;
  for (int it = 0; it < 64; ++it) {
    int idx = base0 + (it << 10) + (threadIdx.x << 2);
    float4 a = *(const float4*)(Sk + idx);
    float4 g = *(const float4*)(Sigma + idx);
    int r = idx >> 9, c = idx & 511;
    float4 reg;
    reg.x = 0.5f*(a.x + g.x); reg.y = 0.5f*(a.y + g.y);
    reg.z = 0.5f*(a.z + g.z); reg.w = 0.5f*(a.w + g.w);
    fro += reg.x*reg.x + reg.y*reg.y + reg.z*reg.z + reg.w*reg.w;
    float4 m;
    m.x = oms*reg.x + ((r == c + 0) ? SHRINKV : 0.f);
    m.y = oms*reg.y + ((r == c + 1) ? SHRINKV : 0.f);
    m.z = oms*reg.z + ((r == c + 2) ? SHRINKV : 0.f);
    m.w = oms*reg.w + ((r == c + 3) ? SHRINKV : 0.f);
    *(float4*)(Mk + idx) = m;
  }
  __shared__ float red[4];
  int lane = threadIdx.x & 63, w = threadIdx.x >> 6;
  for (int o = 32; o > 0; o >>= 1) fro += __shfl_down(fro, o);
  if (lane == 0) red[w] = fro;
  __syncthreads();
  if (threadIdx.x == 0) atomicAdd(&aux[1 + k], red[0] + red[1] + red[2] + red[3]);
}

// In-place blocked Cholesky (lower). One 256-thread WG per class.
// Panel of 64 cols in LDS (stride 65 to kill bank conflicts), SYRK trailing update.
__global__ __launch_bounds__(256) void chol_kernel(float* __restrict__ M) {
  __shared__ float pan[DIM * 65];   // 133120 B
  float* Mk = M + (size_t)blockIdx.x * DD;
  int tid = threadIdx.x;
  for (int p = 0; p < 8; ++p) {
    int p0 = p << 6;
    int H = DIM - p0;
    __syncthreads();   // protect pan vs previous SYRK reads
    for (int idx = tid; idx < H * 64; idx += 256) {
      int i = idx >> 6, j = idx & 63;
      pan[i*65 + j] = Mk[(size_t)(p0 + i)*DIM + p0 + j];
    }
    __syncthreads();
    for (int j = 0; j < 64; ++j) {
      float dv = sqrtf(pan[j*65 + j]);   // uniform read (post-barrier)
      float rinv = 1.0f / dv;
      for (int i = j + 1 + tid; i < H; i += 256) pan[i*65 + j] *= rinv;
      if (tid == 0) Mk[(size_t)(p0 + j)*DIM + p0 + j] = dv;  // diag -> global only
      __syncthreads();
      int Wc = 63 - j;
      if (Wc > 0) {
        int tot = (H - 1 - j) * Wc;
        for (int idx = tid; idx < tot; idx += 256) {
          int i = j + 1 + idx / Wc;
          int cc = j + 1 + idx % Wc;
          pan[i*65 + cc] -= pan[i*65 + j] * pan[cc*65 + j];
        }
      }
      __syncthreads();
    }
    // store L panel (off-diagonals; diag already stored)
    for (int idx = tid; idx < H * 64; idx += 256) {
      int i = idx >> 6, j = idx & 63;
      if (i != j) Mk[(size_t)(p0 + i)*DIM + p0 + j] = pan[i*65 + j];
    }
    // trailing SYRK: M[r][c] -= sum_k Lpanel[r][k]*Lpanel[c][k]
    int nb = 7 - p;
    int tx = tid & 15, ty = tid >> 4;
    for (int bi = 0; bi < nb; ++bi) {
      for (int bj = 0; bj <= bi; ++bj) {
        int r0 = p0 + 64 + (bi << 6);
        int c0 = p0 + 64 + (bj << 6);
        int rr = r0 + (ty << 2);
        int cc = c0 + (tx << 2);
        float accv[4][4];
        #pragma unroll
        for (int i2 = 0; i2 < 4; ++i2) {
          float4 v = *(const float4*)(Mk + (size_t)(rr + i2)*DIM + cc);
          accv[i2][0] = v.x; accv[i2][1] = v.y; accv[i2][2] = v.z; accv[i2][3] = v.w;
        }
        int ra = rr - p0, cb2 = cc - p0;
        for (int kk = 0; kk < 64; ++kk) {
          float a0 = pan[(ra+0)*65 + kk], a1 = pan[(ra+1)*65 + kk];
          float a2 = pan[(ra+2)*65 + kk], a3 = pan[(ra+3)*65 + kk];
          float b0 = pan[(cb2+0)*65 + kk], b1 = pan[(cb2+1)*65 + kk];
          float b2 = pan[(cb2+2)*65 + kk], b3 = pan[(cb2+3)*65 + kk];
          accv[0][0] -= a0*b0; accv[0][1] -= a0*b1; accv[0][2] -= a0*b2; accv[0][3] -= a0*b3;
          accv[1][0] -= a1*b0; accv[1][1] -= a1*b1; accv[1][2] -= a1*b2; accv[1][3] -= a1*b3;
          accv[2][0] -= a2*b0; accv[2][1] -= a2*b1; accv[2][2] -= a2*b2; accv[2][3] -= a2*b3;
          accv[3][0] -= a3*b0; accv[3][1] -= a3*b1; accv[3][2] -= a3*b2; accv[3][3] -= a3*b3;
        }
        #pragma unroll
        for (int i2 = 0; i2 < 4; ++i2) {
          float4 v;
          v.x = accv[i2][0]; v.y = accv[i2][1]; v.z = accv[i2][2]; v.w = accv[i2][3];
          *(float4*)(Mk + (size_t)(rr + i2)*DIM + cc) = v;
        }
      }
    }
  }
}

// W = L^{-1} (lower). 1 wave per (class, 64-column block). Each lane owns one
// column; LDS holds the lane's solution history. 8-row grouping: 1 ds_read
// amortized over 8 FMAs with uniform (scalar) L loads.
__global__ __launch_bounds__(64) void trinv_kernel(const float* __restrict__ M,
                                                   short* __restrict__ W) {
  __shared__ float w[DIM * 64];   // 131072 B
  int kcls = blockIdx.x >> 3;
  int cb = blockIdx.x & 7;
  int c0 = cb << 6;
  int lane = threadIdx.x;
  int c = c0 + lane;
  const float* L = M + (size_t)kcls * DD;
  short* Wk = W + (size_t)kcls * DD;
  int HH = DIM - c0;
  for (int r2 = 0; r2 < HH; ++r2) w[r2*64 + lane] = 0.f;
  for (int rg = c0; rg < DIM; rg += 8) {
    float s[8] = {0.f,0.f,0.f,0.f,0.f,0.f,0.f,0.f};
    for (int kp = c0; kp < rg; ++kp) {
      float wvv = w[(kp - c0)*64 + lane];
      const float* Lp = L + (size_t)rg * DIM + kp;
      #pragma unroll
      for (int i = 0; i < 8; ++i) s[i] += Lp[(size_t)i * DIM] * wvv;
    }
    float wloc[8];
    #pragma unroll
    for (int i = 0; i < 8; ++i) {
      int r = rg + i;
      #pragma unroll
      for (int ii = 0; ii < 8; ++ii) {
        if (ii < i) s[i] += L[(size_t)r*DIM + rg + ii] * wloc[ii];
      }
      float val = 0.f;
      if (r >= c) {
        float rhs = (r == c ? 1.f : 0.f) - s[i];
        val = rhs / L[(size_t)r*DIM + r];
      }
      wloc[i] = val;
      w[(r - c0)*64 + lane] = val;
      Wk[(size_t)r*DIM + c] = f2bf(val);
    }
  }
}

// scores[n][k] = log(prior)-0.25*log(fro2)-0.5*||W_k (x_n-mu_k)||^2 via bf16 MFMA.
// WG: one class, 64 n-rows. Triangular skip: d-chunks 0..jt for j-tile jt.
__global__ __launch_bounds__(256) void score_kernel(const float* __restrict__ X,
                                                    const float* __restrict__ muK,
                                                    const float* __restrict__ cK,
                                                    const short* __restrict__ W,
                                                    const float* __restrict__ aux,
                                                    float* __restrict__ out) {
  __shared__ __align__(16) short diffB[64 * 64];
  __shared__ __align__(16) short WB[64 * 64];
  int bid = blockIdx.x;
  int kc = bid >> 5;
  int n0 = (bid & 31) << 6;
  int tid = threadIdx.x;
  int lane = tid & 63, wv = tid >> 6;
  int srow = tid >> 2;
  int sc4 = (tid & 3) << 4;
  const short* Wk = W + (size_t)kc * DD;
  const float* mu = muK + (size_t)kc * DIM;

  f32x4 acc[8][4];
  #pragma unroll
  for (int a = 0; a < 8; ++a)
    #pragma unroll
    for (int b = 0; b < 4; ++b) { acc[a][b][0]=0.f; acc[a][b][1]=0.f; acc[a][b][2]=0.f; acc[a][b][3]=0.f; }

  int sb0 = ((srow << 7) + (sc4 << 1)) ^ ((srow & 7) << 4);
  int sb1 = ((srow << 7) + (sc4 << 1) + 16) ^ ((srow & 7) << 4);

  #pragma unroll
  for (int dc = 0; dc < 8; ++dc) {
    __syncthreads();  // previous iteration's LDS reads done
    { // stage diff chunk (f32 -> bf16), XOR-swizzled rows
      const float* xr = X + (size_t)(n0 + srow)*DIM + (dc << 6) + sc4;
      const float* mr = mu + (dc << 6) + sc4;
      float4 x0 = *(const float4*)(xr + 0);
      float4 x1 = *(const float4*)(xr + 4);
      float4 x2 = *(const float4*)(xr + 8);
      float4 x3 = *(const float4*)(xr + 12);
      float4 m0 = *(const float4*)(mr + 0);
      float4 m1 = *(const float4*)(mr + 4);
      float4 m2 = *(const float4*)(mr + 8);
      float4 m3 = *(const float4*)(mr + 12);
      bf16x8 h0, h1;
      h0[0]=f2bf(x0.x-m0.x); h0[1]=f2bf(x0.y-m0.y); h0[2]=f2bf(x0.z-m0.z); h0[3]=f2bf(x0.w-m0.w);
      h0[4]=f2bf(x1.x-m1.x); h0[5]=f2bf(x1.y-m1.y); h0[6]=f2bf(x1.z-m1.z); h0[7]=f2bf(x1.w-m1.w);
      h1[0]=f2bf(x2.x-m2.x); h1[1]=f2bf(x2.y-m2.y); h1[2]=f2bf(x2.z-m2.z); h1[3]=f2bf(x2.w-m2.w);
      h1[4]=f2bf(x3.x-m3.x); h1[5]=f2bf(x3.y-m3.y); h1[6]=f2bf(x3.z-m3.z); h1[7]=f2bf(x3.w-m3.w);
      *(bf16x8*)((char*)diffB + sb0) = h0;
      *(bf16x8*)((char*)diffB + sb1) = h1;
    }
    #pragma unroll
    for (int jt = dc; jt < 8; ++jt) {
      __syncthreads();  // diffB ready / previous WB reads done
      {
        const short* wr = Wk + (size_t)((jt << 6) + srow)*DIM + (dc << 6) + sc4;
        uint4 wa = *(const uint4*)(wr);
        uint4 wb2 = *(const uint4*)(wr + 8);
        *(uint4*)((char*)WB + sb0) = wa;
        *(uint4*)((char*)WB + sb1) = wb2;
      }
      __syncthreads();
      int r16 = lane & 15;
      int k8 = (lane >> 4) << 3;
      int arow = (wv << 4) + r16;
      #pragma unroll
      for (int ks = 0; ks < 2; ++ks) {
        bf16x8 af = *(const bf16x8*)((const char*)diffB +
                     (((arow << 7) + (((ks << 5) + k8) << 1)) ^ ((arow & 7) << 4)));
        #pragma unroll
        for (int jj = 0; jj < 4; ++jj) {
          int brow = (jj << 4) + r16;
          bf16x8 bfr = *(const bf16x8*)((const char*)WB +
                       (((brow << 7) + (((ks << 5) + k8) << 1)) ^ ((brow & 7) << 4)));
          acc[jt][jj] = __builtin_amdgcn_mfma_f32_16x16x32_bf16(af, bfr, acc[jt][jj], 0, 0, 0);
        }
      }
    }
  }
  // quad = sum of squares; reduce across the 16 lanes sharing each n
  float qp[4] = {0.f, 0.f, 0.f, 0.f};
  #pragma unroll
  for (int jt2 = 0; jt2 < 8; ++jt2)
    #pragma unroll
    for (int jj = 0; jj < 4; ++jj)
      #pragma unroll
      for (int r = 0; r < 4; ++r) { float y = acc[jt2][jj][r]; qp[r] += y * y; }
  #pragma unroll
  for (int r = 0; r < 4; ++r) {
    qp[r] += __shfl_xor(qp[r], 1);
    qp[r] += __shfl_xor(qp[r], 2);
    qp[r] += __shfl_xor(qp[r], 4);
    qp[r] += __shfl_xor(qp[r], 8);
  }
  float ck = cK[kc];
  float base;
  if (ck == 0.f) base = -INFINITY;
  else base = logf(ck) - logf(aux[0]) - 0.25f * logf(aux[1 + kc]);
  if ((lane & 15) == 0) {
    int nbase = n0 + (wv << 4) + ((lane >> 4) << 2);
    #pragma unroll
    for (int r = 0; r < 4; ++r)
      out[(size_t)(nbase + r)*NCLS + kc] = base - 0.5f * qp[r];
  }
}

extern "C" void kernel_launch(void* const* d_in, const int* in_sizes, int n_in,
                              void* d_out, int out_size, void* d_ws, size_t ws_size,
                              hipStream_t stream) {
  (void)in_sizes; (void)n_in; (void)out_size; (void)ws_size;
  const float* X      = (const float*)d_in[0];
  const float* muK    = (const float*)d_in[1];
  const float* SigmaK = (const float*)d_in[2];
  const float* Sigma  = (const float*)d_in[3];
  const float* cK     = (const float*)d_in[4];
  float* out = (float*)d_out;
  char* ws = (char*)d_ws;
  float* M   = (float*)ws;                                   // 104857600 B
  short* W   = (short*)(ws + (size_t)NCLS * DD * 4);         //  52428800 B
  float* aux = (float*)(ws + (size_t)NCLS * DD * 6);         //       404 B

  aux_kernel<<<1, 128, 0, stream>>>(cK, aux);
  prep_kernel<<<400, 256, 0, stream>>>(SigmaK, Sigma, M, aux);
  chol_kernel<<<NCLS, 256, 0, stream>>>(M);
  trinv_kernel<<<NCLS * 8, 64, 0, stream>>>(M, W);
  score_kernel<<<NCLS * 32, 256, 0, stream>>>(X, muK, cK, W, aux, out);
}

// Round 2
// 2858.818 us; speedup vs baseline: 2.4112x; 2.4112x over previous
//
#include <hip/hip_runtime.h>
#include <math.h>

#define DIM 512
#define NCLS 100
#define NS 2048
#define DD (DIM*DIM)
#define SHRINKV 1e-4f

typedef short bf16x8 __attribute__((ext_vector_type(8)));
typedef short s16x4 __attribute__((ext_vector_type(4)));
typedef float f32x4 __attribute__((ext_vector_type(4)));

static __device__ __forceinline__ short f2bf(float f) {
  unsigned int u = __float_as_uint(f);
  u += 0x7FFFu + ((u >> 16) & 1u);   // round-to-nearest-even
  return (short)(u >> 16);
}

// aux[0] = sum(cK); aux[1+k] zeroed (prep atomically accumulates fro^2 there)
__global__ void aux_kernel(const float* __restrict__ cK, float* __restrict__ aux) {
  __shared__ float red[128];
  int t = threadIdx.x;
  float v = (t < NCLS) ? cK[t] : 0.f;
  if (t < NCLS) aux[1 + t] = 0.f;
  red[t] = v;
  __syncthreads();
  for (int o = 64; o > 0; o >>= 1) {
    if (t < o) red[t] += red[t + o];
    __syncthreads();
  }
  if (t == 0) aux[0] = red[0];
}

// Build M_k = (1-sh)*(0.5*(SigmaK_k+Sigma)) + sh*I ; accumulate ||RegSigma||_F^2
__global__ __launch_bounds__(256) void prep_kernel(const float* __restrict__ SigmaK,
                                                   const float* __restrict__ Sigma,
                                                   float* __restrict__ M,
                                                   float* __restrict__ aux) {
  int b = blockIdx.x;
  int k = b >> 2, chunk = b & 3;
  const float* Sk = SigmaK + (size_t)k * DD;
  float* Mk = M + (size_t)k * DD;
  int base0 = chunk << 16;
  float fro = 0.f;
  const float oms = 1.0f - SHRINKV;
  for (int it = 0; it < 64; ++it) {
    int idx = base0 + (it << 10) + (threadIdx.x << 2);
    float4 a = *(const float4*)(Sk + idx);
    float4 g = *(const float4*)(Sigma + idx);
    int r = idx >> 9, c = idx & 511;
    float4 reg;
    reg.x = 0.5f*(a.x + g.x); reg.y = 0.5f*(a.y + g.y);
    reg.z = 0.5f*(a.z + g.z); reg.w = 0.5f*(a.w + g.w);
    fro += reg.x*reg.x + reg.y*reg.y + reg.z*reg.z + reg.w*reg.w;
    float4 m;
    m.x = oms*reg.x + ((r == c + 0) ? SHRINKV : 0.f);
    m.y = oms*reg.y + ((r == c + 1) ? SHRINKV : 0.f);
    m.z = oms*reg.z + ((r == c + 2) ? SHRINKV : 0.f);
    m.w = oms*reg.w + ((r == c + 3) ? SHRINKV : 0.f);
    *(float4*)(Mk + idx) = m;
  }
  __shared__ float red[4];
  int lane = threadIdx.x & 63, w = threadIdx.x >> 6;
  for (int o = 32; o > 0; o >>= 1) fro += __shfl_down(fro, o);
  if (lane == 0) red[w] = fro;
  __syncthreads();
  if (threadIdx.x == 0) atomicAdd(&aux[1 + k], red[0] + red[1] + red[2] + red[3]);
}

// In-place blocked Cholesky (lower). One 256-thread WG per class.
__global__ __launch_bounds__(256) void chol_kernel(float* __restrict__ M) {
  __shared__ float pan[DIM * 65];   // 133120 B
  float* Mk = M + (size_t)blockIdx.x * DD;
  int tid = threadIdx.x;
  for (int p = 0; p < 8; ++p) {
    int p0 = p << 6;
    int H = DIM - p0;
    __syncthreads();   // protect pan vs previous SYRK reads
    for (int idx = tid; idx < H * 64; idx += 256) {
      int i = idx >> 6, j = idx & 63;
      pan[i*65 + j] = Mk[(size_t)(p0 + i)*DIM + p0 + j];
    }
    __syncthreads();
    for (int j = 0; j < 64; ++j) {
      float dv = sqrtf(pan[j*65 + j]);   // uniform read (post-barrier)
      float rinv = 1.0f / dv;
      for (int i = j + 1 + tid; i < H; i += 256) pan[i*65 + j] *= rinv;
      if (tid == 0) Mk[(size_t)(p0 + j)*DIM + p0 + j] = dv;  // diag -> global only
      __syncthreads();
      int Wc = 63 - j;
      if (Wc > 0) {
        int tot = (H - 1 - j) * Wc;
        for (int idx = tid; idx < tot; idx += 256) {
          int i = j + 1 + idx / Wc;
          int cc = j + 1 + idx % Wc;
          pan[i*65 + cc] -= pan[i*65 + j] * pan[cc*65 + j];
        }
      }
      __syncthreads();
    }
    // store L panel (off-diagonals; diag already stored)
    for (int idx = tid; idx < H * 64; idx += 256) {
      int i = idx >> 6, j = idx & 63;
      if (i != j) Mk[(size_t)(p0 + i)*DIM + p0 + j] = pan[i*65 + j];
    }
    // trailing SYRK: M[r][c] -= sum_k Lpanel[r][k]*Lpanel[c][k]
    int nb = 7 - p;
    int tx = tid & 15, ty = tid >> 4;
    for (int bi = 0; bi < nb; ++bi) {
      for (int bj = 0; bj <= bi; ++bj) {
        int r0 = p0 + 64 + (bi << 6);
        int c0 = p0 + 64 + (bj << 6);
        int rr = r0 + (ty << 2);
        int cc = c0 + (tx << 2);
        float accv[4][4];
        #pragma unroll
        for (int i2 = 0; i2 < 4; ++i2) {
          float4 v = *(const float4*)(Mk + (size_t)(rr + i2)*DIM + cc);
          accv[i2][0] = v.x; accv[i2][1] = v.y; accv[i2][2] = v.z; accv[i2][3] = v.w;
        }
        int ra = rr - p0, cb2 = cc - p0;
        for (int kk = 0; kk < 64; ++kk) {
          float a0 = pan[(ra+0)*65 + kk], a1 = pan[(ra+1)*65 + kk];
          float a2 = pan[(ra+2)*65 + kk], a3 = pan[(ra+3)*65 + kk];
          float b0 = pan[(cb2+0)*65 + kk], b1 = pan[(cb2+1)*65 + kk];
          float b2 = pan[(cb2+2)*65 + kk], b3 = pan[(cb2+3)*65 + kk];
          accv[0][0] -= a0*b0; accv[0][1] -= a0*b1; accv[0][2] -= a0*b2; accv[0][3] -= a0*b3;
          accv[1][0] -= a1*b0; accv[1][1] -= a1*b1; accv[1][2] -= a1*b2; accv[1][3] -= a1*b3;
          accv[2][0] -= a2*b0; accv[2][1] -= a2*b1; accv[2][2] -= a2*b2; accv[2][3] -= a2*b3;
          accv[3][0] -= a3*b0; accv[3][1] -= a3*b1; accv[3][2] -= a3*b2; accv[3][3] -= a3*b3;
        }
        #pragma unroll
        for (int i2 = 0; i2 < 4; ++i2) {
          float4 v;
          v.x = accv[i2][0]; v.y = accv[i2][1]; v.z = accv[i2][2]; v.w = accv[i2][3];
          *(float4*)(Mk + (size_t)(rr + i2)*DIM + cc) = v;
        }
      }
    }
  }
}

// Invert the 8 diagonal 64x64 blocks of each L in place (M <- W_ii), also bf16 -> W.
// 1 wave per (class, diag block). Per-lane column solve, full register history.
__global__ __launch_bounds__(64) void diaginv_kernel(float* __restrict__ M,
                                                     short* __restrict__ Wb) {
  __shared__ float pan[64 * 64];   // 16384 B
  int kcls = blockIdx.x >> 3;
  int ib = blockIdx.x & 7;
  int i0 = ib << 6;
  int lane = threadIdx.x;
  float* Mk = M + (size_t)kcls * DD;
  short* Wk = Wb + (size_t)kcls * DD;
  for (int r = 0; r < 64; ++r)
    pan[r*64 + lane] = Mk[(size_t)(i0 + r)*DIM + i0 + lane];
  __syncthreads();
  float w[64];
  #pragma unroll
  for (int r = 0; r < 64; ++r) {
    float s = 0.f;
    #pragma unroll
    for (int k = 0; k + 4 <= r; k += 4) {
      float4 lv = *(const float4*)(pan + r*64 + k);
      s += lv.x*w[k] + lv.y*w[k+1] + lv.z*w[k+2] + lv.w*w[k+3];
    }
    #pragma unroll
    for (int k = r & ~3; k < r; ++k) s += pan[r*64 + k] * w[k];
    float rinv = 1.0f / pan[r*64 + r];
    float rhs = ((r == lane) ? 1.0f : 0.0f) - s;
    w[r] = rhs * rinv;   // exact 0 for r < lane
  }
  #pragma unroll
  for (int r = 0; r < 64; ++r) {
    Mk[(size_t)(i0 + r)*DIM + i0 + lane] = w[r];
    Wk[(size_t)(i0 + r)*DIM + i0 + lane] = f2bf(w[r]);
  }
}

// Off-diagonal blocks of W = L^{-1}, in place in M (+ bf16 copy).
// One 256-thread WG per class; for i=1..7, j<i:
//   W_ij = -W_ii * (sum_{k=j}^{i-1} L_ik * W_kj)
// In-place is safe with increasing (i,j): block (i,j) is never read as an
// L-operand after being overwritten (reads use k >= j' > j), and W_kj reads
// come from rows < i.
__global__ __launch_bounds__(256) void sweep_kernel(float* __restrict__ M,
                                                    short* __restrict__ Wb) {
  __shared__ float TA[64 * 68];   // A-operand, stored TRANSPOSED: TA[k*68+r] = A[r][k]
  __shared__ float TB[64 * 68];   // B-operand, row-major
  float* Mk = M + (size_t)blockIdx.x * DD;
  short* Wk = Wb + (size_t)blockIdx.x * DD;
  int tid = threadIdx.x;
  int ty = tid >> 4, tx = tid & 15;        // 16x16 threads, 4x4 outputs each
  int sr = tid >> 2, sq = (tid & 3) << 4;  // staging: row sr, cols sq..sq+15

  auto stageT = [&](const float* base) {   // base: 64x64 block, row stride DIM
    const float4* s = (const float4*)(base + (size_t)sr * DIM + sq);
    #pragma unroll
    for (int t4 = 0; t4 < 4; ++t4) {
      float4 v = s[t4];
      TA[(sq + t4*4 + 0)*68 + sr] = v.x;
      TA[(sq + t4*4 + 1)*68 + sr] = v.y;
      TA[(sq + t4*4 + 2)*68 + sr] = v.z;
      TA[(sq + t4*4 + 3)*68 + sr] = v.w;
    }
  };
  auto stageN = [&](const float* base) {
    const float4* s = (const float4*)(base + (size_t)sr * DIM + sq);
    float4* d = (float4*)(TB + sr * 68 + sq);
    #pragma unroll
    for (int t4 = 0; t4 < 4; ++t4) d[t4] = s[t4];
  };

  for (int i = 1; i < 8; ++i) {
    for (int j = 0; j < i; ++j) {
      float acc[4][4];
      #pragma unroll
      for (int a = 0; a < 4; ++a)
        #pragma unroll
        for (int b = 0; b < 4; ++b) acc[a][b] = 0.f;
      for (int k = j; k < i; ++k) {
        __syncthreads();   // TA/TB safe to overwrite
        stageT(Mk + ((size_t)(i << 6))*DIM + (k << 6));   // L_ik (transposed)
        stageN(Mk + ((size_t)(k << 6))*DIM + (j << 6));   // W_kj
        __syncthreads();
        #pragma unroll 16
        for (int kk = 0; kk < 64; ++kk) {
          float4 av = *(const float4*)(TA + kk*68 + (ty << 2));
          float4 bv = *(const float4*)(TB + kk*68 + (tx << 2));
          float a4[4] = {av.x, av.y, av.z, av.w};
          float b4[4] = {bv.x, bv.y, bv.z, bv.w};
          #pragma unroll
          for (int ir = 0; ir < 4; ++ir)
            #pragma unroll
            for (int ic = 0; ic < 4; ++ic) acc[ir][ic] += a4[ir] * b4[ic];
        }
      }
      __syncthreads();   // done reading TA/TB
      stageT(Mk + ((size_t)(i << 6))*DIM + (i << 6));     // W_ii (transposed)
      #pragma unroll
      for (int ir = 0; ir < 4; ++ir) {
        float4 v;
        v.x = acc[ir][0]; v.y = acc[ir][1]; v.z = acc[ir][2]; v.w = acc[ir][3];
        *(float4*)(TB + ((ty << 2) + ir)*68 + (tx << 2)) = v;   // S -> TB
      }
      __syncthreads();
      float r2[4][4];
      #pragma unroll
      for (int a = 0; a < 4; ++a)
        #pragma unroll
        for (int b = 0; b < 4; ++b) r2[a][b] = 0.f;
      #pragma unroll 16
      for (int kk = 0; kk < 64; ++kk) {
        float4 av = *(const float4*)(TA + kk*68 + (ty << 2));
        float4 bv = *(const float4*)(TB + kk*68 + (tx << 2));
        float a4[4] = {av.x, av.y, av.z, av.w};
        float b4[4] = {bv.x, bv.y, bv.z, bv.w};
        #pragma unroll
        for (int ir = 0; ir < 4; ++ir)
          #pragma unroll
          for (int ic = 0; ic < 4; ++ic) r2[ir][ic] -= a4[ir] * b4[ic];
      }
      #pragma unroll
      for (int ir = 0; ir < 4; ++ir) {
        int row = (i << 6) + (ty << 2) + ir;
        size_t base = (size_t)row * DIM + (j << 6) + (tx << 2);
        float4 v;
        v.x = r2[ir][0]; v.y = r2[ir][1]; v.z = r2[ir][2]; v.w = r2[ir][3];
        *(float4*)(Mk + base) = v;
        s16x4 h;
        h[0] = f2bf(r2[ir][0]); h[1] = f2bf(r2[ir][1]);
        h[2] = f2bf(r2[ir][2]); h[3] = f2bf(r2[ir][3]);
        *(s16x4*)(Wk + base) = h;
      }
    }
  }
}

// scores[n][k] = log(prior)-0.25*log(fro2)-0.5*||W_k (x_n-mu_k)||^2 via bf16 MFMA.
__global__ __launch_bounds__(256) void score_kernel(const float* __restrict__ X,
                                                    const float* __restrict__ muK,
                                                    const float* __restrict__ cK,
                                                    const short* __restrict__ W,
                                                    const float* __restrict__ aux,
                                                    float* __restrict__ out) {
  __shared__ __align__(16) short diffB[64 * 64];
  __shared__ __align__(16) short WB[64 * 64];
  int bid = blockIdx.x;
  int kc = bid >> 5;
  int n0 = (bid & 31) << 6;
  int tid = threadIdx.x;
  int lane = tid & 63, wv = tid >> 6;
  int srow = tid >> 2;
  int sc4 = (tid & 3) << 4;
  const short* Wk = W + (size_t)kc * DD;
  const float* mu = muK + (size_t)kc * DIM;

  f32x4 acc[8][4];
  #pragma unroll
  for (int a = 0; a < 8; ++a)
    #pragma unroll
    for (int b = 0; b < 4; ++b) { acc[a][b][0]=0.f; acc[a][b][1]=0.f; acc[a][b][2]=0.f; acc[a][b][3]=0.f; }

  int sb0 = ((srow << 7) + (sc4 << 1)) ^ ((srow & 7) << 4);
  int sb1 = ((srow << 7) + (sc4 << 1) + 16) ^ ((srow & 7) << 4);

  #pragma unroll
  for (int dc = 0; dc < 8; ++dc) {
    __syncthreads();
    {
      const float* xr = X + (size_t)(n0 + srow)*DIM + (dc << 6) + sc4;
      const float* mr = mu + (dc << 6) + sc4;
      float4 x0 = *(const float4*)(xr + 0);
      float4 x1 = *(const float4*)(xr + 4);
      float4 x2 = *(const float4*)(xr + 8);
      float4 x3 = *(const float4*)(xr + 12);
      float4 m0 = *(const float4*)(mr + 0);
      float4 m1 = *(const float4*)(mr + 4);
      float4 m2 = *(const float4*)(mr + 8);
      float4 m3 = *(const float4*)(mr + 12);
      bf16x8 h0, h1;
      h0[0]=f2bf(x0.x-m0.x); h0[1]=f2bf(x0.y-m0.y); h0[2]=f2bf(x0.z-m0.z); h0[3]=f2bf(x0.w-m0.w);
      h0[4]=f2bf(x1.x-m1.x); h0[5]=f2bf(x1.y-m1.y); h0[6]=f2bf(x1.z-m1.z); h0[7]=f2bf(x1.w-m1.w);
      h1[0]=f2bf(x2.x-m2.x); h1[1]=f2bf(x2.y-m2.y); h1[2]=f2bf(x2.z-m2.z); h1[3]=f2bf(x2.w-m2.w);
      h1[4]=f2bf(x3.x-m3.x); h1[5]=f2bf(x3.y-m3.y); h1[6]=f2bf(x3.z-m3.z); h1[7]=f2bf(x3.w-m3.w);
      *(bf16x8*)((char*)diffB + sb0) = h0;
      *(bf16x8*)((char*)diffB + sb1) = h1;
    }
    #pragma unroll
    for (int jt = dc; jt < 8; ++jt) {
      __syncthreads();
      {
        const short* wr = Wk + (size_t)((jt << 6) + srow)*DIM + (dc << 6) + sc4;
        uint4 wa = *(const uint4*)(wr);
        uint4 wb2 = *(const uint4*)(wr + 8);
        *(uint4*)((char*)WB + sb0) = wa;
        *(uint4*)((char*)WB + sb1) = wb2;
      }
      __syncthreads();
      int r16 = lane & 15;
      int k8 = (lane >> 4) << 3;
      int arow = (wv << 4) + r16;
      #pragma unroll
      for (int ks = 0; ks < 2; ++ks) {
        bf16x8 af = *(const bf16x8*)((const char*)diffB +
                     (((arow << 7) + (((ks << 5) + k8) << 1)) ^ ((arow & 7) << 4)));
        #pragma unroll
        for (int jj = 0; jj < 4; ++jj) {
          int brow = (jj << 4) + r16;
          bf16x8 bfr = *(const bf16x8*)((const char*)WB +
                       (((brow << 7) + (((ks << 5) + k8) << 1)) ^ ((brow & 7) << 4)));
          acc[jt][jj] = __builtin_amdgcn_mfma_f32_16x16x32_bf16(af, bfr, acc[jt][jj], 0, 0, 0);
        }
      }
    }
  }
  float qp[4] = {0.f, 0.f, 0.f, 0.f};
  #pragma unroll
  for (int jt2 = 0; jt2 < 8; ++jt2)
    #pragma unroll
    for (int jj = 0; jj < 4; ++jj)
      #pragma unroll
      for (int r = 0; r < 4; ++r) { float y = acc[jt2][jj][r]; qp[r] += y * y; }
  #pragma unroll
  for (int r = 0; r < 4; ++r) {
    qp[r] += __shfl_xor(qp[r], 1);
    qp[r] += __shfl_xor(qp[r], 2);
    qp[r] += __shfl_xor(qp[r], 4);
    qp[r] += __shfl_xor(qp[r], 8);
  }
  float ck = cK[kc];
  float base;
  if (ck == 0.f) base = -INFINITY;
  else base = logf(ck) - logf(aux[0]) - 0.25f * logf(aux[1 + kc]);
  if ((lane & 15) == 0) {
    int nbase = n0 + (wv << 4) + ((lane >> 4) << 2);
    #pragma unroll
    for (int r = 0; r < 4; ++r)
      out[(size_t)(nbase + r)*NCLS + kc] = base - 0.5f * qp[r];
  }
}

extern "C" void kernel_launch(void* const* d_in, const int* in_sizes, int n_in,
                              void* d_out, int out_size, void* d_ws, size_t ws_size,
                              hipStream_t stream) {
  (void)in_sizes; (void)n_in; (void)out_size; (void)ws_size;
  const float* X      = (const float*)d_in[0];
  const float* muK    = (const float*)d_in[1];
  const float* SigmaK = (const float*)d_in[2];
  const float* Sigma  = (const float*)d_in[3];
  const float* cK     = (const float*)d_in[4];
  float* out = (float*)d_out;
  char* ws = (char*)d_ws;
  float* M   = (float*)ws;                                   // 104857600 B
  short* W   = (short*)(ws + (size_t)NCLS * DD * 4);         //  52428800 B
  float* aux = (float*)(ws + (size_t)NCLS * DD * 6);         //       404 B

  aux_kernel<<<1, 128, 0, stream>>>(cK, aux);
  prep_kernel<<<400, 256, 0, stream>>>(SigmaK, Sigma, M, aux);
  chol_kernel<<<NCLS, 256, 0, stream>>>(M);
  diaginv_kernel<<<NCLS * 8, 64, 0, stream>>>(M, W);
  sweep_kernel<<<NCLS, 256, 0, stream>>>(M, W);
  score_kernel<<<NCLS * 32, 256, 0, stream>>>(X, muK, cK, W, aux, out);
}

// Round 3
// 909.377 us; speedup vs baseline: 7.5801x; 3.1437x over previous
//
#include <hip/hip_runtime.h>
#include <math.h>

#define DIM 512
#define NCLS 100
#define NS 2048
#define DD (DIM*DIM)
#define SHRINKV 1e-4f

typedef short bf16x8 __attribute__((ext_vector_type(8)));
typedef short s16x4 __attribute__((ext_vector_type(4)));
typedef float f32x4 __attribute__((ext_vector_type(4)));

static __device__ __forceinline__ short f2bf(float f) {
  unsigned int u = __float_as_uint(f);
  u += 0x7FFFu + ((u >> 16) & 1u);   // round-to-nearest-even
  return (short)(u >> 16);
}

// aux[0] = sum(cK); aux[1+k] zeroed (prep atomically accumulates fro^2 there)
__global__ void aux_kernel(const float* __restrict__ cK, float* __restrict__ aux) {
  __shared__ float red[128];
  int t = threadIdx.x;
  float v = (t < NCLS) ? cK[t] : 0.f;
  if (t < NCLS) aux[1 + t] = 0.f;
  red[t] = v;
  __syncthreads();
  for (int o = 64; o > 0; o >>= 1) {
    if (t < o) red[t] += red[t + o];
    __syncthreads();
  }
  if (t == 0) aux[0] = red[0];
}

// Build M_k = (1-sh)*(0.5*(SigmaK_k+Sigma)) + sh*I ; accumulate ||RegSigma||_F^2
__global__ __launch_bounds__(256) void prep_kernel(const float* __restrict__ SigmaK,
                                                   const float* __restrict__ Sigma,
                                                   float* __restrict__ M,
                                                   float* __restrict__ aux) {
  int b = blockIdx.x;
  int k = b >> 2, chunk = b & 3;
  const float* Sk = SigmaK + (size_t)k * DD;
  float* Mk = M + (size_t)k * DD;
  int base0 = chunk << 16;
  float fro = 0.f;
  const float oms = 1.0f - SHRINKV;
  for (int it = 0; it < 64; ++it) {
    int idx = base0 + (it << 10) + (threadIdx.x << 2);
    float4 a = *(const float4*)(Sk + idx);
    float4 g = *(const float4*)(Sigma + idx);
    int r = idx >> 9, c = idx & 511;
    float4 reg;
    reg.x = 0.5f*(a.x + g.x); reg.y = 0.5f*(a.y + g.y);
    reg.z = 0.5f*(a.z + g.z); reg.w = 0.5f*(a.w + g.w);
    fro += reg.x*reg.x + reg.y*reg.y + reg.z*reg.z + reg.w*reg.w;
    float4 m;
    m.x = oms*reg.x + ((r == c + 0) ? SHRINKV : 0.f);
    m.y = oms*reg.y + ((r == c + 1) ? SHRINKV : 0.f);
    m.z = oms*reg.z + ((r == c + 2) ? SHRINKV : 0.f);
    m.w = oms*reg.w + ((r == c + 3) ? SHRINKV : 0.f);
    *(float4*)(Mk + idx) = m;
  }
  __shared__ float red[4];
  int lane = threadIdx.x & 63, w = threadIdx.x >> 6;
  for (int o = 32; o > 0; o >>= 1) fro += __shfl_down(fro, o);
  if (lane == 0) red[w] = fro;
  __syncthreads();
  if (threadIdx.x == 0) atomicAdd(&aux[1 + k], red[0] + red[1] + red[2] + red[3]);
}

// Factor diag block p (64x64 Cholesky, shuffle-based, registers) and store its
// INVERSE into M(p,p) (f32) and W(p,p) (bf16). One wave per class.
// Nothing downstream needs L_pp itself: TRSM uses inv, sweep uses inv.
__global__ __launch_bounds__(64) void fdiag_kernel(float* __restrict__ M,
                                                   short* __restrict__ Wb, int p) {
  __shared__ float Llds[64 * 68];
  int kcls = blockIdx.x;
  int lane = threadIdx.x;
  int p0 = p << 6;
  float* Mk = M + (size_t)kcls * DD;
  short* Wk = Wb + (size_t)kcls * DD;
  // lane r holds row r of the diag block
  float row[64];
  {
    const float* src = Mk + (size_t)(p0 + lane) * DIM + p0;
    #pragma unroll
    for (int c4 = 0; c4 < 64; c4 += 4) {
      float4 v = *(const float4*)(src + c4);
      row[c4] = v.x; row[c4+1] = v.y; row[c4+2] = v.z; row[c4+3] = v.w;
    }
  }
  // right-looking Cholesky; after step j, row[j] = L[r][j]
  #pragma unroll
  for (int j = 0; j < 64; ++j) {
    float diagv = __shfl(row[j], j);
    float dv = sqrtf(diagv);
    float rinv = 1.0f / dv;
    float myLj = row[j] * rinv;      // lane r >= j: L[r][j]; lane j gets dv
    row[j] = myLj;
    #pragma unroll
    for (int c = j + 1; c < 64; ++c)
      row[c] = fmaf(-myLj, __shfl(myLj, c), row[c]);
  }
  // L rows -> LDS (zero above diag), then per-lane column inverse solve
  #pragma unroll
  for (int c = 0; c < 64; ++c)
    Llds[lane * 68 + c] = (c <= lane) ? row[c] : 0.f;
  __syncthreads();
  float w[64];
  #pragma unroll
  for (int r = 0; r < 64; ++r) {
    float s = 0.f;
    #pragma unroll
    for (int kk = 0; kk + 4 <= r; kk += 4) {
      float4 lv = *(const float4*)(Llds + r*68 + kk);
      s += lv.x*w[kk] + lv.y*w[kk+1] + lv.z*w[kk+2] + lv.w*w[kk+3];
    }
    #pragma unroll
    for (int kk = r & ~3; kk < r; ++kk) s += Llds[r*68 + kk] * w[kk];
    float rhs = ((r == lane) ? 1.0f : 0.0f) - s;
    w[r] = rhs / Llds[r*68 + r];     // exact 0 for r < lane
  }
  #pragma unroll
  for (int r = 0; r < 64; ++r) {
    Mk[(size_t)(p0 + r)*DIM + p0 + lane] = w[r];
    Wk[(size_t)(p0 + r)*DIM + p0 + lane] = f2bf(w[r]);
  }
}

// TRSM: for i > p, L_ip = A_ip * inv(L_pp)^T. One WG per (class, i).
__global__ __launch_bounds__(256) void trsm_kernel(float* __restrict__ M, int p) {
  __shared__ float TA[64 * 68];   // TA[m][r] = A_ip[r][m]
  __shared__ float TB[64 * 68];   // TB[m][c] = inv[c][m]
  int n = 7 - p;
  int cls = blockIdx.x / n;
  int bi = blockIdx.x % n;
  int i = p + 1 + bi;
  float* Mk = M + (size_t)cls * DD;
  int tid = threadIdx.x;
  int ty = tid >> 4, tx = tid & 15;
  int sr = tid >> 2, sq = (tid & 3) << 4;
  {
    const float* a = Mk + (size_t)((i << 6) + sr)*DIM + (p << 6) + sq;
    const float* b = Mk + (size_t)((p << 6) + sr)*DIM + (p << 6) + sq;
    #pragma unroll
    for (int t4 = 0; t4 < 4; ++t4) {
      float4 va = *(const float4*)(a + 4*t4);
      TA[(sq+4*t4+0)*68+sr]=va.x; TA[(sq+4*t4+1)*68+sr]=va.y;
      TA[(sq+4*t4+2)*68+sr]=va.z; TA[(sq+4*t4+3)*68+sr]=va.w;
      float4 vb = *(const float4*)(b + 4*t4);
      TB[(sq+4*t4+0)*68+sr]=vb.x; TB[(sq+4*t4+1)*68+sr]=vb.y;
      TB[(sq+4*t4+2)*68+sr]=vb.z; TB[(sq+4*t4+3)*68+sr]=vb.w;
    }
  }
  __syncthreads();
  float acc[4][4];
  #pragma unroll
  for (int a = 0; a < 4; ++a)
    #pragma unroll
    for (int b = 0; b < 4; ++b) acc[a][b] = 0.f;
  #pragma unroll 16
  for (int m = 0; m < 64; ++m) {
    float4 av = *(const float4*)(TA + m*68 + (ty << 2));
    float4 bv = *(const float4*)(TB + m*68 + (tx << 2));
    float a4[4] = {av.x, av.y, av.z, av.w};
    float b4[4] = {bv.x, bv.y, bv.z, bv.w};
    #pragma unroll
    for (int ir = 0; ir < 4; ++ir)
      #pragma unroll
      for (int ic = 0; ic < 4; ++ic) acc[ir][ic] += a4[ir] * b4[ic];
  }
  #pragma unroll
  for (int q = 0; q < 4; ++q) {
    float4 v; v.x = acc[q][0]; v.y = acc[q][1]; v.z = acc[q][2]; v.w = acc[q][3];
    *(float4*)(Mk + (size_t)((i << 6) + (ty << 2) + q)*DIM + (p << 6) + (tx << 2)) = v;
  }
}

// SYRK: for p < j <= i, A_ij -= L_ip * L_jp^T. One WG per (class, pair).
__global__ __launch_bounds__(256) void syrk_kernel(float* __restrict__ M, int p) {
  __shared__ float TA[64 * 68];   // TA[m][r] = L_ip[r][m]
  __shared__ float TB[64 * 68];   // TB[m][c] = L_jp[c][m]
  int n = 7 - p;
  int T = n * (n + 1) / 2;
  int cls = blockIdx.x / T;
  int t = blockIdx.x % T;
  int bi = 0;
  while (t > bi) { t -= bi + 1; ++bi; }
  int i = p + 1 + bi, j = p + 1 + t;
  float* Mk = M + (size_t)cls * DD;
  int tid = threadIdx.x;
  int ty = tid >> 4, tx = tid & 15;
  int sr = tid >> 2, sq = (tid & 3) << 4;
  {
    const float* a = Mk + (size_t)((i << 6) + sr)*DIM + (p << 6) + sq;
    const float* b = Mk + (size_t)((j << 6) + sr)*DIM + (p << 6) + sq;
    #pragma unroll
    for (int t4 = 0; t4 < 4; ++t4) {
      float4 va = *(const float4*)(a + 4*t4);
      TA[(sq+4*t4+0)*68+sr]=va.x; TA[(sq+4*t4+1)*68+sr]=va.y;
      TA[(sq+4*t4+2)*68+sr]=va.z; TA[(sq+4*t4+3)*68+sr]=va.w;
      float4 vb = *(const float4*)(b + 4*t4);
      TB[(sq+4*t4+0)*68+sr]=vb.x; TB[(sq+4*t4+1)*68+sr]=vb.y;
      TB[(sq+4*t4+2)*68+sr]=vb.z; TB[(sq+4*t4+3)*68+sr]=vb.w;
    }
  }
  __syncthreads();
  float acc[4][4];
  #pragma unroll
  for (int a = 0; a < 4; ++a)
    #pragma unroll
    for (int b = 0; b < 4; ++b) acc[a][b] = 0.f;
  #pragma unroll 16
  for (int m = 0; m < 64; ++m) {
    float4 av = *(const float4*)(TA + m*68 + (ty << 2));
    float4 bv = *(const float4*)(TB + m*68 + (tx << 2));
    float a4[4] = {av.x, av.y, av.z, av.w};
    float b4[4] = {bv.x, bv.y, bv.z, bv.w};
    #pragma unroll
    for (int ir = 0; ir < 4; ++ir)
      #pragma unroll
      for (int ic = 0; ic < 4; ++ic) acc[ir][ic] += a4[ir] * b4[ic];
  }
  #pragma unroll
  for (int q = 0; q < 4; ++q) {
    float* dst = Mk + (size_t)((i << 6) + (ty << 2) + q)*DIM + (j << 6) + (tx << 2);
    float4 v = *(const float4*)dst;
    v.x -= acc[q][0]; v.y -= acc[q][1]; v.z -= acc[q][2]; v.w -= acc[q][3];
    *(float4*)dst = v;
  }
}

// Sweep iteration i: W_ij = -W_ii * (sum_{k=j}^{i-1} L_ik * W_kj) for all j < i.
// W f32 blocks live in M's UPPER triangle: W_kj (k>=j) stored at block (j,k);
// diag blocks of M hold W_ii = inv(L_ii). L row i (lower) is never overwritten.
// One WG per (class, j). Also emits bf16 W block (i,j).
__global__ __launch_bounds__(256) void sweep_kernel(float* __restrict__ M,
                                                    short* __restrict__ Wb, int i) {
  __shared__ float TL[64 * 68];
  __shared__ float TW[64 * 68];
  int cls = blockIdx.x / i;
  int j = blockIdx.x % i;
  float* Mk = M + (size_t)cls * DD;
  short* Wk = Wb + (size_t)cls * DD;
  int tid = threadIdx.x;
  int ty = tid >> 4, tx = tid & 15;
  int sr = tid >> 2, sq = (tid & 3) << 4;
  float acc[4][4];
  #pragma unroll
  for (int a = 0; a < 4; ++a)
    #pragma unroll
    for (int b = 0; b < 4; ++b) acc[a][b] = 0.f;
  for (int k = j; k < i; ++k) {
    __syncthreads();
    {
      // TL[m][r] = L_ik[r][m]  (block (i,k), lower — still L)
      const float* a = Mk + (size_t)((i << 6) + sr)*DIM + (k << 6) + sq;
      // TW[m][c] = W_kj[m][c]  (block (j,k): diag if k==j else upper)
      const float* b = Mk + (size_t)((j << 6) + sr)*DIM + (k << 6) + sq;
      #pragma unroll
      for (int t4 = 0; t4 < 4; ++t4) {
        float4 va = *(const float4*)(a + 4*t4);
        TL[(sq+4*t4+0)*68+sr]=va.x; TL[(sq+4*t4+1)*68+sr]=va.y;
        TL[(sq+4*t4+2)*68+sr]=va.z; TL[(sq+4*t4+3)*68+sr]=va.w;
        *(float4*)(TW + sr*68 + sq + 4*t4) = *(const float4*)(b + 4*t4);
      }
    }
    __syncthreads();
    #pragma unroll 16
    for (int m = 0; m < 64; ++m) {
      float4 av = *(const float4*)(TL + m*68 + (ty << 2));
      float4 bv = *(const float4*)(TW + m*68 + (tx << 2));
      float a4[4] = {av.x, av.y, av.z, av.w};
      float b4[4] = {bv.x, bv.y, bv.z, bv.w};
      #pragma unroll
      for (int ir = 0; ir < 4; ++ir)
        #pragma unroll
        for (int ic = 0; ic < 4; ++ic) acc[ir][ic] += a4[ir] * b4[ic];
    }
  }
  __syncthreads();
  // S -> TW (row-major), W_ii -> TL (transposed)
  #pragma unroll
  for (int q = 0; q < 4; ++q) {
    float4 v; v.x = acc[q][0]; v.y = acc[q][1]; v.z = acc[q][2]; v.w = acc[q][3];
    *(float4*)(TW + ((ty << 2) + q)*68 + (tx << 2)) = v;
  }
  {
    const float* a = Mk + (size_t)((i << 6) + sr)*DIM + (i << 6) + sq;
    #pragma unroll
    for (int t4 = 0; t4 < 4; ++t4) {
      float4 va = *(const float4*)(a + 4*t4);
      TL[(sq+4*t4+0)*68+sr]=va.x; TL[(sq+4*t4+1)*68+sr]=va.y;
      TL[(sq+4*t4+2)*68+sr]=va.z; TL[(sq+4*t4+3)*68+sr]=va.w;
    }
  }
  __syncthreads();
  float r2[4][4];
  #pragma unroll
  for (int a = 0; a < 4; ++a)
    #pragma unroll
    for (int b = 0; b < 4; ++b) r2[a][b] = 0.f;
  #pragma unroll 16
  for (int m = 0; m < 64; ++m) {
    float4 av = *(const float4*)(TL + m*68 + (ty << 2));
    float4 bv = *(const float4*)(TW + m*68 + (tx << 2));
    float a4[4] = {av.x, av.y, av.z, av.w};
    float b4[4] = {bv.x, bv.y, bv.z, bv.w};
    #pragma unroll
    for (int ir = 0; ir < 4; ++ir)
      #pragma unroll
      for (int ic = 0; ic < 4; ++ic) r2[ir][ic] += a4[ir] * b4[ic];
  }
  #pragma unroll
  for (int q = 0; q < 4; ++q) {
    int a = (ty << 2) + q;
    float4 v; v.x = -r2[q][0]; v.y = -r2[q][1]; v.z = -r2[q][2]; v.w = -r2[q][3];
    *(float4*)(Mk + (size_t)((j << 6) + a)*DIM + (i << 6) + (tx << 2)) = v;   // W f32 (upper)
    s16x4 h;
    h[0] = f2bf(v.x); h[1] = f2bf(v.y); h[2] = f2bf(v.z); h[3] = f2bf(v.w);
    *(s16x4*)(Wk + (size_t)((i << 6) + a)*DIM + (j << 6) + (tx << 2)) = h;    // W bf16 (lower)
  }
}

// scores[n][k] = log(prior)-0.25*log(fro2)-0.5*||W_k (x_n-mu_k)||^2 via bf16 MFMA.
__global__ __launch_bounds__(256) void score_kernel(const float* __restrict__ X,
                                                    const float* __restrict__ muK,
                                                    const float* __restrict__ cK,
                                                    const short* __restrict__ W,
                                                    const float* __restrict__ aux,
                                                    float* __restrict__ out) {
  __shared__ __align__(16) short diffB[64 * 64];
  __shared__ __align__(16) short WB[64 * 64];
  int bid = blockIdx.x;
  int kc = bid >> 5;
  int n0 = (bid & 31) << 6;
  int tid = threadIdx.x;
  int lane = tid & 63, wv = tid >> 6;
  int srow = tid >> 2;
  int sc4 = (tid & 3) << 4;
  const short* Wk = W + (size_t)kc * DD;
  const float* mu = muK + (size_t)kc * DIM;

  f32x4 acc[8][4];
  #pragma unroll
  for (int a = 0; a < 8; ++a)
    #pragma unroll
    for (int b = 0; b < 4; ++b) { acc[a][b][0]=0.f; acc[a][b][1]=0.f; acc[a][b][2]=0.f; acc[a][b][3]=0.f; }

  int sb0 = ((srow << 7) + (sc4 << 1)) ^ ((srow & 7) << 4);
  int sb1 = ((srow << 7) + (sc4 << 1) + 16) ^ ((srow & 7) << 4);

  #pragma unroll
  for (int dc = 0; dc < 8; ++dc) {
    __syncthreads();
    {
      const float* xr = X + (size_t)(n0 + srow)*DIM + (dc << 6) + sc4;
      const float* mr = mu + (dc << 6) + sc4;
      float4 x0 = *(const float4*)(xr + 0);
      float4 x1 = *(const float4*)(xr + 4);
      float4 x2 = *(const float4*)(xr + 8);
      float4 x3 = *(const float4*)(xr + 12);
      float4 m0 = *(const float4*)(mr + 0);
      float4 m1 = *(const float4*)(mr + 4);
      float4 m2 = *(const float4*)(mr + 8);
      float4 m3 = *(const float4*)(mr + 12);
      bf16x8 h0, h1;
      h0[0]=f2bf(x0.x-m0.x); h0[1]=f2bf(x0.y-m0.y); h0[2]=f2bf(x0.z-m0.z); h0[3]=f2bf(x0.w-m0.w);
      h0[4]=f2bf(x1.x-m1.x); h0[5]=f2bf(x1.y-m1.y); h0[6]=f2bf(x1.z-m1.z); h0[7]=f2bf(x1.w-m1.w);
      h1[0]=f2bf(x2.x-m2.x); h1[1]=f2bf(x2.y-m2.y); h1[2]=f2bf(x2.z-m2.z); h1[3]=f2bf(x2.w-m2.w);
      h1[4]=f2bf(x3.x-m3.x); h1[5]=f2bf(x3.y-m3.y); h1[6]=f2bf(x3.z-m3.z); h1[7]=f2bf(x3.w-m3.w);
      *(bf16x8*)((char*)diffB + sb0) = h0;
      *(bf16x8*)((char*)diffB + sb1) = h1;
    }
    #pragma unroll
    for (int jt = dc; jt < 8; ++jt) {
      __syncthreads();
      {
        const short* wr = Wk + (size_t)((jt << 6) + srow)*DIM + (dc << 6) + sc4;
        uint4 wa = *(const uint4*)(wr);
        uint4 wb2 = *(const uint4*)(wr + 8);
        *(uint4*)((char*)WB + sb0) = wa;
        *(uint4*)((char*)WB + sb1) = wb2;
      }
      __syncthreads();
      int r16 = lane & 15;
      int k8 = (lane >> 4) << 3;
      int arow = (wv << 4) + r16;
      #pragma unroll
      for (int ks = 0; ks < 2; ++ks) {
        bf16x8 af = *(const bf16x8*)((const char*)diffB +
                     (((arow << 7) + (((ks << 5) + k8) << 1)) ^ ((arow & 7) << 4)));
        #pragma unroll
        for (int jj = 0; jj < 4; ++jj) {
          int brow = (jj << 4) + r16;
          bf16x8 bfr = *(const bf16x8*)((const char*)WB +
                       (((brow << 7) + (((ks << 5) + k8) << 1)) ^ ((brow & 7) << 4)));
          acc[jt][jj] = __builtin_amdgcn_mfma_f32_16x16x32_bf16(af, bfr, acc[jt][jj], 0, 0, 0);
        }
      }
    }
  }
  float qp[4] = {0.f, 0.f, 0.f, 0.f};
  #pragma unroll
  for (int jt2 = 0; jt2 < 8; ++jt2)
    #pragma unroll
    for (int jj = 0; jj < 4; ++jj)
      #pragma unroll
      for (int r = 0; r < 4; ++r) { float y = acc[jt2][jj][r]; qp[r] += y * y; }
  #pragma unroll
  for (int r = 0; r < 4; ++r) {
    qp[r] += __shfl_xor(qp[r], 1);
    qp[r] += __shfl_xor(qp[r], 2);
    qp[r] += __shfl_xor(qp[r], 4);
    qp[r] += __shfl_xor(qp[r], 8);
  }
  float ck = cK[kc];
  float base;
  if (ck == 0.f) base = -INFINITY;
  else base = logf(ck) - logf(aux[0]) - 0.25f * logf(aux[1 + kc]);
  if ((lane & 15) == 0) {
    int nbase = n0 + (wv << 4) + ((lane >> 4) << 2);
    #pragma unroll
    for (int r = 0; r < 4; ++r)
      out[(size_t)(nbase + r)*NCLS + kc] = base - 0.5f * qp[r];
  }
}

extern "C" void kernel_launch(void* const* d_in, const int* in_sizes, int n_in,
                              void* d_out, int out_size, void* d_ws, size_t ws_size,
                              hipStream_t stream) {
  (void)in_sizes; (void)n_in; (void)out_size; (void)ws_size;
  const float* X      = (const float*)d_in[0];
  const float* muK    = (const float*)d_in[1];
  const float* SigmaK = (const float*)d_in[2];
  const float* Sigma  = (const float*)d_in[3];
  const float* cK     = (const float*)d_in[4];
  float* out = (float*)d_out;
  char* ws = (char*)d_ws;
  float* M   = (float*)ws;                                   // 104857600 B
  short* W   = (short*)(ws + (size_t)NCLS * DD * 4);         //  52428800 B
  float* aux = (float*)(ws + (size_t)NCLS * DD * 6);         //       404 B

  aux_kernel<<<1, 128, 0, stream>>>(cK, aux);
  prep_kernel<<<400, 256, 0, stream>>>(SigmaK, Sigma, M, aux);
  for (int p = 0; p < 8; ++p) {
    fdiag_kernel<<<NCLS, 64, 0, stream>>>(M, W, p);
    int n = 7 - p;
    if (n > 0) {
      trsm_kernel<<<NCLS * n, 256, 0, stream>>>(M, p);
      syrk_kernel<<<NCLS * (n * (n + 1) / 2), 256, 0, stream>>>(M, p);
    }
  }
  for (int i = 1; i < 8; ++i)
    sweep_kernel<<<NCLS * i, 256, 0, stream>>>(M, W, i);
  score_kernel<<<NCLS * 32, 256, 0, stream>>>(X, muK, cK, W, aux, out);
}